// Round 3
// baseline (977.054 us; speedup 1.0000x reference)
//
#include <hip/hip_runtime.h>
#include <stdint.h>

// Problem constants
#define N_TOK 4096
#define DIM   1024
#define HFRAC 2048
#define HSW   4096
#define NEXP  8
#define NFRAC 4
#define TOPK  2
#define TOTAL_ROWS (N_TOK * TOPK)   // 8192, always exact
#define PAD_ROWS   (TOTAL_ROWS + 128)

typedef unsigned short u16;
typedef __bf16 bf16x8 __attribute__((ext_vector_type(8)));
typedef float  floatx4 __attribute__((ext_vector_type(4)));

struct alignas(8)  us4 { u16 v[4]; };

__device__ __forceinline__ u16 f32_to_bf16_raw(float f) {
    union { float f; uint32_t u; } v; v.f = f;
    uint32_t u = v.u;
    uint32_t r = 0x7FFFu + ((u >> 16) & 1u);   // round-to-nearest-even
    return (u16)((u + r) >> 16);
}
__device__ __forceinline__ float bf16_raw_to_f32(u16 h) {
    union { uint32_t u; float f; } v; v.u = ((uint32_t)h) << 16;
    return v.f;
}

// async global->LDS, 16B per lane. LDS dest is wave-uniform base + lane*16.
__device__ __forceinline__ void async_copy16(const u16* g, u16* s) {
    __builtin_amdgcn_global_load_lds(
        (const __attribute__((address_space(1))) uint32_t*)g,
        (__attribute__((address_space(3))) uint32_t*)s, 16, 0, 0);
}

// Stage a 128x64 bf16 tile (global row stride ld) into 8KB-row-major LDS with
// XOR chunk swizzle: LDS[r][c] holds global[r][c ^ (r&7)]. Global side gets the
// permutation (per-lane address); LDS side stays lane-contiguous as required.
// Each wave stages rows [wave*32, wave*32+32).
__device__ __forceinline__ void stage_tile(const u16* g, int ld, u16* s,
                                           int wave, int lane) {
    const int r0 = wave * 32 + (lane >> 3);
    const int c8 = ((lane & 7) ^ ((lane >> 3) & 7)) << 3;   // (r0&7) == ((lane>>3)&7)
    const u16* gp = g + (size_t)r0 * ld + c8;
#pragma unroll
    for (int it = 0; it < 4; ++it)
        async_copy16(gp + (size_t)(it * 8) * ld, s + (wave * 32 + it * 8) * 64);
}

// read logical 8-elem chunk `q` of LDS row `row` (undo swizzle), as b128
__device__ __forceinline__ bf16x8 frag_ld(const u16* s, int row, int q) {
    return *reinterpret_cast<const bf16x8*>(&s[row * 64 + ((q ^ (row & 7)) << 3)]);
}

// ---------------------------------------------------------------- fp32 -> bf16
__global__ __launch_bounds__(256) void cvt_kernel(
    const float* __restrict__ in, u16* __restrict__ out) {
    size_t i = (size_t)blockIdx.x * 256 + threadIdx.x;   // float4 index
    float4 v = reinterpret_cast<const float4*>(in)[i];
    us4 o = { f32_to_bf16_raw(v.x), f32_to_bf16_raw(v.y),
              f32_to_bf16_raw(v.z), f32_to_bf16_raw(v.w) };
    reinterpret_cast<us4*>(out)[i] = o;
}

// ---------------------------------------------------------------- router
__global__ __launch_bounds__(256) void router_kernel(
    const float* __restrict__ x, const float* __restrict__ rw,
    int* __restrict__ re, float* __restrict__ rc, int* __restrict__ counts) {
    const int token = blockIdx.x * 4 + (threadIdx.x >> 6);
    const int lane  = threadIdx.x & 63;
    const float* xr = x + (size_t)token * DIM;

    float acc[NEXP];
#pragma unroll
    for (int e = 0; e < NEXP; ++e) acc[e] = 0.0f;
#pragma unroll
    for (int i = 0; i < DIM / 64; ++i) {
        int k = lane + i * 64;
        float xv = xr[k];
#pragma unroll
        for (int e = 0; e < NEXP; ++e) acc[e] += xv * rw[e * DIM + k];
    }
#pragma unroll
    for (int e = 0; e < NEXP; ++e) {
#pragma unroll
        for (int off = 32; off > 0; off >>= 1) acc[e] += __shfl_down(acc[e], off);
    }
    if (lane == 0) {
        float mx = acc[0];
#pragma unroll
        for (int e = 1; e < NEXP; ++e) mx = fmaxf(mx, acc[e]);
        float w[NEXP]; float s = 0.0f;
#pragma unroll
        for (int e = 0; e < NEXP; ++e) { w[e] = expf(acc[e] - mx); s += w[e]; }
        float inv = 1.0f / s;
#pragma unroll
        for (int e = 0; e < NEXP; ++e) w[e] *= inv;
        int i1 = 0;
#pragma unroll
        for (int e = 1; e < NEXP; ++e) if (w[e] > w[i1]) i1 = e;
        int i2 = (i1 == 0) ? 1 : 0;
#pragma unroll
        for (int e = 0; e < NEXP; ++e) if (e != i1 && w[e] > w[i2]) i2 = e;
        float denom = fmaxf(w[i1] + w[i2], 1e-9f);
        re[token]         = i1; rc[token]         = w[i1] / denom;
        re[N_TOK + token] = i2; rc[N_TOK + token] = w[i2] / denom;
        atomicAdd(&counts[i1], 1);
        atomicAdd(&counts[i2], 1);
    }
}

__global__ void offsets_kernel(const int* __restrict__ counts,
                               int* __restrict__ offs) {
    if (threadIdx.x == 0 && blockIdx.x == 0) {
        int a = 0;
#pragma unroll
        for (int e = 0; e < NEXP; ++e) { offs[e] = a; a += counts[e]; }
    }
}

__global__ __launch_bounds__(256) void scatter_kernel(
    const int* __restrict__ re, const float* __restrict__ rc,
    const int* __restrict__ offs, int* __restrict__ cursor,
    int* __restrict__ rowtok, float* __restrict__ co) {
    int token = blockIdx.x * 256 + threadIdx.x;
#pragma unroll
    for (int slot = 0; slot < TOPK; ++slot) {
        int e = re[slot * N_TOK + token];
        int i = atomicAdd(&cursor[e], 1);
        int r = offs[e] + i;
        rowtok[r] = token | (slot << 16);
        co[r]     = rc[slot * N_TOK + token];
    }
}

// gather+norm: Ag[r] = (e<4) ? bf16(rmsnorm(x[token], frac_rms[e])) : bf16(x[token])
__global__ __launch_bounds__(256) void gather_norm_kernel(
    const float* __restrict__ x, const float* __restrict__ frac_rms,
    const int* __restrict__ rowtok, const int* __restrict__ offs,
    u16* __restrict__ Ag) {
    const int r   = blockIdx.x;
    const int tid = threadIdx.x;
    if (r >= TOTAL_ROWS) {                 // zero-fill pad rows
        us4 z = {0, 0, 0, 0};
        reinterpret_cast<us4*>(Ag + (size_t)r * DIM)[tid] = z;
        return;
    }
    int e = 0;
#pragma unroll
    for (int i = 1; i < NEXP; ++i) if (r >= offs[i]) e = i;
    const int token = rowtok[r] & 0xFFFF;
    float4 v = reinterpret_cast<const float4*>(x + (size_t)token * DIM)[tid];
    if (e < NFRAC) {
        float ss = v.x * v.x + v.y * v.y + v.z * v.z + v.w * v.w;
#pragma unroll
        for (int off = 32; off > 0; off >>= 1) ss += __shfl_down(ss, off);
        __shared__ float red[4];
        if ((tid & 63) == 0) red[tid >> 6] = ss;
        __syncthreads();
        float scale = rsqrtf((red[0] + red[1] + red[2] + red[3]) * (1.0f / DIM) + 1e-6f);
        float4 wv = reinterpret_cast<const float4*>(frac_rms + (size_t)e * DIM)[tid];
        v.x *= scale * wv.x; v.y *= scale * wv.y;
        v.z *= scale * wv.z; v.w *= scale * wv.w;
    }
    us4 o = { f32_to_bf16_raw(v.x), f32_to_bf16_raw(v.y),
              f32_to_bf16_raw(v.z), f32_to_bf16_raw(v.w) };
    reinterpret_cast<us4*>(Ag + (size_t)r * DIM)[tid] = o;
}

// ---------------------------------------------------------------- GEMM params
#define BM 128
#define BN 128
#define BK 64

// fused gemm1 (all experts): g = bf16(silu(A@W1^T) * (A@W3^T)) into gbuf
__global__ __launch_bounds__(256) void gemm1_kernel(
    const u16* __restrict__ Ag,
    const u16* __restrict__ w1f, const u16* __restrict__ w3f,
    const u16* __restrict__ w1s, const u16* __restrict__ w3s,
    u16* __restrict__ gbuf,
    const int* __restrict__ counts, const int* __restrict__ offs) {
    const int e   = blockIdx.z;
    const int cnt = counts[e];
    const int m0  = blockIdx.y * BM;
    if (m0 >= cnt) return;
    const int Ne = (e < NFRAC) ? HFRAC : HSW;
    const int n0 = blockIdx.x * BN;
    if (n0 >= Ne) return;
    const int rowbase = offs[e];
    const u16* W1 = (e < NFRAC) ? w1f + (size_t)e * HFRAC * DIM
                                : w1s + (size_t)(e - NFRAC) * HSW * DIM;
    const u16* W3 = (e < NFRAC) ? w3f + (size_t)e * HFRAC * DIM
                                : w3s + (size_t)(e - NFRAC) * HSW * DIM;
    const u16* A = Ag + (size_t)(rowbase + m0) * DIM;

    __shared__ u16 sA[BM * BK];    // 16 KB each
    __shared__ u16 sB1[BN * BK];
    __shared__ u16 sB3[BN * BK];

    const int tid  = threadIdx.x;
    const int wave = tid >> 6;
    const int lane = tid & 63;
    const int wm = wave >> 1, wn = wave & 1;
    const int fr = lane & 15;        // fragment row-within-16
    const int quad = lane >> 4;

    floatx4 acc1[4][4], acc3[4][4];
    floatx4 zero = { 0.f, 0.f, 0.f, 0.f };
#pragma unroll
    for (int mt = 0; mt < 4; ++mt)
#pragma unroll
        for (int nt = 0; nt < 4; ++nt) { acc1[mt][nt] = zero; acc3[mt][nt] = zero; }

    const u16* gB1 = W1 + (size_t)n0 * DIM;
    const u16* gB3 = W3 + (size_t)n0 * DIM;

    for (int k0 = 0; k0 < DIM; k0 += BK) {
        stage_tile(A   + k0, DIM, sA,  wave, lane);
        stage_tile(gB1 + k0, DIM, sB1, wave, lane);
        stage_tile(gB3 + k0, DIM, sB3, wave, lane);
        __syncthreads();
#pragma unroll
        for (int ks = 0; ks < 2; ++ks) {
            const int q = ks * 4 + quad;
            bf16x8 af[4];
#pragma unroll
            for (int mt = 0; mt < 4; ++mt)
                af[mt] = frag_ld(sA, wm * 64 + mt * 16 + fr, q);
#pragma unroll
            for (int nt = 0; nt < 4; ++nt) {
                bf16x8 b1 = frag_ld(sB1, wn * 64 + nt * 16 + fr, q);
                bf16x8 b3 = frag_ld(sB3, wn * 64 + nt * 16 + fr, q);
#pragma unroll
                for (int mt = 0; mt < 4; ++mt) {
                    acc1[mt][nt] = __builtin_amdgcn_mfma_f32_16x16x32_bf16(
                        af[mt], b1, acc1[mt][nt], 0, 0, 0);
                    acc3[mt][nt] = __builtin_amdgcn_mfma_f32_16x16x32_bf16(
                        af[mt], b3, acc3[mt][nt], 0, 0, 0);
                }
            }
        }
        __syncthreads();
    }
#pragma unroll
    for (int mt = 0; mt < 4; ++mt)
#pragma unroll
        for (int nt = 0; nt < 4; ++nt)
#pragma unroll
            for (int r = 0; r < 4; ++r) {
                int row_local = m0 + wm * 64 + mt * 16 + quad * 4 + r;
                if (row_local >= cnt) continue;
                int col = n0 + wn * 64 + nt * 16 + fr;
                float h1 = acc1[mt][nt][r];
                float h3 = acc3[mt][nt][r];
                float g = (h1 / (1.0f + expf(-h1))) * h3;
                gbuf[(size_t)(rowbase + row_local) * HSW + col] = f32_to_bf16_raw(g);
            }
}

// fused gemm2 (all experts): y = g @ W2^T; atomically add combined result to out
__global__ __launch_bounds__(256) void gemm2_kernel(
    const u16* __restrict__ gbuf,
    const u16* __restrict__ w2f, const u16* __restrict__ w2s,
    const u16* __restrict__ Ag, const float* __restrict__ x,
    const float* __restrict__ frac_gamma,
    const int* __restrict__ rowtok, const float* __restrict__ co,
    const int* __restrict__ counts, const int* __restrict__ offs,
    float* __restrict__ out) {
    const int e   = blockIdx.z;
    const int cnt = counts[e];
    const int m0  = blockIdx.y * BM;
    if (m0 >= cnt) return;
    const int n0 = blockIdx.x * BN;
    const int Ke = (e < NFRAC) ? HFRAC : HSW;
    const int rowbase = offs[e];
    const u16* W2 = (e < NFRAC) ? w2f + (size_t)e * DIM * HFRAC
                                : w2s + (size_t)(e - NFRAC) * DIM * HSW;
    const u16* A = gbuf + (size_t)(rowbase + m0) * HSW;

    __shared__ u16 sA[BM * BK];
    __shared__ u16 sB[BN * BK];

    const int tid  = threadIdx.x;
    const int wave = tid >> 6;
    const int lane = tid & 63;
    const int wm = wave >> 1, wn = wave & 1;
    const int fr = lane & 15;
    const int quad = lane >> 4;

    floatx4 acc[4][4];
    floatx4 zero = { 0.f, 0.f, 0.f, 0.f };
#pragma unroll
    for (int mt = 0; mt < 4; ++mt)
#pragma unroll
        for (int nt = 0; nt < 4; ++nt) acc[mt][nt] = zero;

    const u16* gB = W2 + (size_t)n0 * Ke;

    for (int k0 = 0; k0 < Ke; k0 += BK) {
        stage_tile(A  + k0, HSW, sA, wave, lane);
        stage_tile(gB + k0, Ke,  sB, wave, lane);
        __syncthreads();
#pragma unroll
        for (int ks = 0; ks < 2; ++ks) {
            const int q = ks * 4 + quad;
            bf16x8 af[4];
#pragma unroll
            for (int mt = 0; mt < 4; ++mt)
                af[mt] = frag_ld(sA, wm * 64 + mt * 16 + fr, q);
#pragma unroll
            for (int nt = 0; nt < 4; ++nt) {
                bf16x8 b = frag_ld(sB, wn * 64 + nt * 16 + fr, q);
#pragma unroll
                for (int mt = 0; mt < 4; ++mt)
                    acc[mt][nt] = __builtin_amdgcn_mfma_f32_16x16x32_bf16(
                        af[mt], b, acc[mt][nt], 0, 0, 0);
            }
        }
        __syncthreads();
    }
    const float* gamma = frac_gamma + (size_t)e * DIM;
#pragma unroll
    for (int mt = 0; mt < 4; ++mt)
#pragma unroll
        for (int nt = 0; nt < 4; ++nt)
#pragma unroll
            for (int rr = 0; rr < 4; ++rr) {
                int row_local = m0 + wm * 64 + mt * 16 + quad * 4 + rr;
                if (row_local >= cnt) continue;
                int r = rowbase + row_local;
                int col = n0 + wn * 64 + nt * 16 + fr;
                int info  = rowtok[r];
                int token = info & 0xFFFF;
                float coef = co[r];
                float y = acc[mt][nt][rr];
                float val;
                if (e < NFRAC) {
                    float xn = bf16_raw_to_f32(Ag[(size_t)r * DIM + col]);
                    val = coef * (gamma[col] * (xn + y) + x[(size_t)token * DIM + col]);
                } else {
                    val = coef * y;
                }
                atomicAdd(&out[(size_t)token * DIM + col], val);
            }
}

// ---------------------------------------------------------------- launch
extern "C" void kernel_launch(void* const* d_in, const int* in_sizes, int n_in,
                              void* d_out, int out_size, void* d_ws, size_t ws_size,
                              hipStream_t stream) {
    const float* x          = (const float*)d_in[0];
    const float* router_w   = (const float*)d_in[1];
    const float* frac_rms   = (const float*)d_in[2];
    const float* frac_w1    = (const float*)d_in[3];
    const float* frac_w2    = (const float*)d_in[4];
    const float* frac_w3    = (const float*)d_in[5];
    const float* frac_gamma = (const float*)d_in[6];
    const float* sw_w1      = (const float*)d_in[7];
    const float* sw_w2      = (const float*)d_in[8];
    const float* sw_w3      = (const float*)d_in[9];
    float* out = (float*)d_out;

    const size_t MB = 1u << 20;
    char* ws = (char*)d_ws;
    // meta (<256 KB)
    int*   counts = (int*)ws;
    int*   cursor = (int*)(ws + 32);
    int*   offs   = (int*)(ws + 64);
    int*   re     = (int*)(ws + 1024);
    float* rc     = (float*)(ws + 36864);
    int*   rowtok = (int*)(ws + 73728);
    float* co     = (float*)(ws + 110592);
    // big buffers
    u16* Ag   = (u16*)(ws + 1 * MB);     // PAD_ROWS*1024*2 = 17.04 MB
    u16* gbuf = (u16*)(ws + 19 * MB);    // PAD_ROWS*4096*2 = 68.2 MB
    u16* w1f  = (u16*)(ws + 84 * MB);    // 16 MB
    u16* w3f  = (u16*)(ws + 100 * MB);   // 16 MB
    u16* w1s  = (u16*)(ws + 116 * MB);   // 32 MB
    u16* w3s  = (u16*)(ws + 148 * MB);   // 32 MB -> end 180 MB
    // w2 cache aliases w1/w3 cache (converted after gemm1 has consumed w1/w3)
    u16* w2f  = (u16*)(ws + 84 * MB);    // 16 MB
    u16* w2s  = (u16*)(ws + 100 * MB);   // 32 MB

    hipMemsetAsync(ws, 0, 256, stream);                                  // counts+cursor
    hipMemsetAsync(d_out, 0, (size_t)N_TOK * DIM * sizeof(float), stream);

    // weight cache: w1, w3 (w2 later, aliased)
    cvt_kernel<<<(NFRAC * HFRAC * DIM) / 1024, 256, 0, stream>>>(frac_w1, w1f);
    cvt_kernel<<<(NFRAC * HFRAC * DIM) / 1024, 256, 0, stream>>>(frac_w3, w3f);
    cvt_kernel<<<(NFRAC * HSW * DIM) / 1024, 256, 0, stream>>>(sw_w1, w1s);
    cvt_kernel<<<(NFRAC * HSW * DIM) / 1024, 256, 0, stream>>>(sw_w3, w3s);

    router_kernel<<<N_TOK / 4, 256, 0, stream>>>(x, router_w, re, rc, counts);
    offsets_kernel<<<1, 64, 0, stream>>>(counts, offs);
    scatter_kernel<<<N_TOK / 256, 256, 0, stream>>>(re, rc, offs, cursor, rowtok, co);
    gather_norm_kernel<<<PAD_ROWS, 256, 0, stream>>>(x, frac_rms, rowtok, offs, Ag);

    gemm1_kernel<<<dim3(HSW / BN, TOTAL_ROWS / BM, NEXP), 256, 0, stream>>>(
        Ag, w1f, w3f, w1s, w3s, gbuf, counts, offs);

    cvt_kernel<<<(NFRAC * DIM * HFRAC) / 1024, 256, 0, stream>>>(frac_w2, w2f);
    cvt_kernel<<<(NFRAC * DIM * HSW) / 1024, 256, 0, stream>>>(sw_w2, w2s);

    gemm2_kernel<<<dim3(DIM / BN, TOTAL_ROWS / BM, NEXP), 256, 0, stream>>>(
        gbuf, w2f, w2s, Ag, x, frac_gamma, rowtok, co, counts, offs, out);
}

// Round 4
// 916.167 us; speedup vs baseline: 1.0665x; 1.0665x over previous
//
#include <hip/hip_runtime.h>
#include <stdint.h>

// Problem constants
#define N_TOK 4096
#define DIM   1024
#define HFRAC 2048
#define HSW   4096
#define NEXP  8
#define NFRAC 4
#define TOPK  2
#define TOTAL_ROWS (N_TOK * TOPK)   // 8192, always exact
#define PAD_ROWS   (TOTAL_ROWS + 128)
#define WL1_MAX 144   // >= sum_e nh_e*ceil(cnt_e/128)  (<= 2*8192/128 + 12 = 140)
#define WL2_MAX 72    // >= sum_e ceil(cnt_e/128)        (<= 8192/128 + 8 = 72)

typedef unsigned short u16;
typedef __bf16 bf16x8 __attribute__((ext_vector_type(8)));
typedef float  floatx4 __attribute__((ext_vector_type(4)));

struct alignas(8)  us4 { u16 v[4]; };

__device__ __forceinline__ u16 f32_to_bf16_raw(float f) {
    union { float f; uint32_t u; } v; v.f = f;
    uint32_t u = v.u;
    uint32_t r = 0x7FFFu + ((u >> 16) & 1u);   // round-to-nearest-even
    return (u16)((u + r) >> 16);
}
__device__ __forceinline__ float bf16_raw_to_f32(u16 h) {
    union { uint32_t u; float f; } v; v.u = ((uint32_t)h) << 16;
    return v.f;
}

// async global->LDS, 16B per lane. LDS dest is wave-uniform base + lane*16.
__device__ __forceinline__ void async_copy16(const u16* g, u16* s) {
    __builtin_amdgcn_global_load_lds(
        (const __attribute__((address_space(1))) uint32_t*)g,
        (__attribute__((address_space(3))) uint32_t*)s, 16, 0, 0);
}

// Stage a 128x64 bf16 tile (global row stride ld) into row-major LDS with XOR
// chunk swizzle: LDS[r][c8] holds global[r][c8 ^ (r&7)]. Wave stages 32 rows.
__device__ __forceinline__ void stage_tile(const u16* g, int ld, u16* s,
                                           int wave, int lane) {
    const int r0 = wave * 32 + (lane >> 3);
    const int c8 = ((lane & 7) ^ ((lane >> 3) & 7)) << 3;
    const u16* gp = g + (size_t)r0 * ld + c8;
#pragma unroll
    for (int it = 0; it < 4; ++it)
        async_copy16(gp + (size_t)(it * 8) * ld, s + (wave * 32 + it * 8) * 64);
}

// read logical 8-elem chunk `q` of LDS row `row` (undo swizzle), as b128
__device__ __forceinline__ bf16x8 frag_ld(const u16* s, int row, int q) {
    return *reinterpret_cast<const bf16x8*>(&s[row * 64 + ((q ^ (row & 7)) << 3)]);
}

// ---------------------------------------------------------------- fp32 -> bf16
// 16 float4 per thread; grid = elems / (4*4096)
__global__ __launch_bounds__(256) void cvt_kernel(
    const float* __restrict__ in, u16* __restrict__ out) {
    size_t base = (size_t)blockIdx.x * 4096 + threadIdx.x;   // float4 index
#pragma unroll
    for (int j = 0; j < 16; ++j) {
        size_t i = base + j * 256;
        float4 v = reinterpret_cast<const float4*>(in)[i];
        us4 o = { f32_to_bf16_raw(v.x), f32_to_bf16_raw(v.y),
                  f32_to_bf16_raw(v.z), f32_to_bf16_raw(v.w) };
        reinterpret_cast<us4*>(out)[i] = o;
    }
}

// ---------------------------------------------------------------- router
__global__ __launch_bounds__(256) void router_kernel(
    const float* __restrict__ x, const float* __restrict__ rw,
    int* __restrict__ re, float* __restrict__ rc, int* __restrict__ counts) {
    const int token = blockIdx.x * 4 + (threadIdx.x >> 6);
    const int lane  = threadIdx.x & 63;
    const float* xr = x + (size_t)token * DIM;

    float acc[NEXP];
#pragma unroll
    for (int e = 0; e < NEXP; ++e) acc[e] = 0.0f;
#pragma unroll
    for (int i = 0; i < DIM / 64; ++i) {
        int k = lane + i * 64;
        float xv = xr[k];
#pragma unroll
        for (int e = 0; e < NEXP; ++e) acc[e] += xv * rw[e * DIM + k];
    }
#pragma unroll
    for (int e = 0; e < NEXP; ++e) {
#pragma unroll
        for (int off = 32; off > 0; off >>= 1) acc[e] += __shfl_down(acc[e], off);
    }
    if (lane == 0) {
        float mx = acc[0];
#pragma unroll
        for (int e = 1; e < NEXP; ++e) mx = fmaxf(mx, acc[e]);
        float w[NEXP]; float s = 0.0f;
#pragma unroll
        for (int e = 0; e < NEXP; ++e) { w[e] = expf(acc[e] - mx); s += w[e]; }
        float inv = 1.0f / s;
#pragma unroll
        for (int e = 0; e < NEXP; ++e) w[e] *= inv;
        int i1 = 0;
#pragma unroll
        for (int e = 1; e < NEXP; ++e) if (w[e] > w[i1]) i1 = e;
        int i2 = (i1 == 0) ? 1 : 0;
#pragma unroll
        for (int e = 0; e < NEXP; ++e) if (e != i1 && w[e] > w[i2]) i2 = e;
        float denom = fmaxf(w[i1] + w[i2], 1e-9f);
        re[token]         = i1; rc[token]         = w[i1] / denom;
        re[N_TOK + token] = i2; rc[N_TOK + token] = w[i2] / denom;
        atomicAdd(&counts[i1], 1);
        atomicAdd(&counts[i2], 1);
    }
}

__global__ void offsets_kernel(const int* __restrict__ counts,
                               int* __restrict__ offs) {
    if (threadIdx.x == 0 && blockIdx.x == 0) {
        int a = 0;
#pragma unroll
        for (int e = 0; e < NEXP; ++e) { offs[e] = a; a += counts[e]; }
    }
}

// exact block worklists from counts. entry: e | (m0<<4) | (half<<24)
__global__ void build_wl_kernel(const int* __restrict__ counts,
                                uint32_t* __restrict__ wl1,
                                uint32_t* __restrict__ wl2) {
    if (threadIdx.x == 0 && blockIdx.x == 0) {
        int i1 = 0, i2 = 0;
        for (int e = 0; e < NEXP; ++e) {
            int cnt = counts[e];
            int nh  = (e < NFRAC) ? 1 : 2;
            for (int m0 = 0; m0 < cnt; m0 += 128) {
                wl2[i2++] = (uint32_t)(e | (m0 << 4));
                for (int h = 0; h < nh; ++h)
                    wl1[i1++] = (uint32_t)(e | (m0 << 4) | (h << 24));
            }
        }
        while (i1 < WL1_MAX) wl1[i1++] = 0xFFFFFFFFu;
        while (i2 < WL2_MAX) wl2[i2++] = 0xFFFFFFFFu;
    }
}

__global__ __launch_bounds__(256) void scatter_kernel(
    const int* __restrict__ re, const float* __restrict__ rc,
    const int* __restrict__ offs, int* __restrict__ cursor,
    int* __restrict__ rowtok, float* __restrict__ co) {
    int token = blockIdx.x * 256 + threadIdx.x;
#pragma unroll
    for (int slot = 0; slot < TOPK; ++slot) {
        int e = re[slot * N_TOK + token];
        int i = atomicAdd(&cursor[e], 1);
        int r = offs[e] + i;
        rowtok[r] = token | (slot << 16);
        co[r]     = rc[slot * N_TOK + token];
    }
}

// gather+norm, one row per WAVE (4 rows/block), grid = PAD_ROWS/4
__global__ __launch_bounds__(256) void gather_norm_kernel(
    const float* __restrict__ x, const float* __restrict__ frac_rms,
    const int* __restrict__ rowtok, const int* __restrict__ offs,
    u16* __restrict__ Ag) {
    const int r    = blockIdx.x * 4 + (threadIdx.x >> 6);
    const int lane = threadIdx.x & 63;
    us4* dst = reinterpret_cast<us4*>(Ag + (size_t)r * DIM);
    if (r >= TOTAL_ROWS) {                 // zero-fill pad rows
        us4 z = {0, 0, 0, 0};
#pragma unroll
        for (int j = 0; j < 4; ++j) dst[lane + 64 * j] = z;
        return;
    }
    int e = 0;
#pragma unroll
    for (int i = 1; i < NEXP; ++i) if (r >= offs[i]) e = i;
    const int token = rowtok[r] & 0xFFFF;
    const float4* xr = reinterpret_cast<const float4*>(x + (size_t)token * DIM);
    float4 v[4];
#pragma unroll
    for (int j = 0; j < 4; ++j) v[j] = xr[lane + 64 * j];
    if (e < NFRAC) {
        float ss = 0.0f;
#pragma unroll
        for (int j = 0; j < 4; ++j)
            ss += v[j].x * v[j].x + v[j].y * v[j].y + v[j].z * v[j].z + v[j].w * v[j].w;
#pragma unroll
        for (int off = 32; off > 0; off >>= 1) ss += __shfl_xor(ss, off);
        float scale = rsqrtf(ss * (1.0f / DIM) + 1e-6f);
        const float4* wr = reinterpret_cast<const float4*>(frac_rms + (size_t)e * DIM);
#pragma unroll
        for (int j = 0; j < 4; ++j) {
            float4 wv = wr[lane + 64 * j];
            v[j].x *= scale * wv.x; v[j].y *= scale * wv.y;
            v[j].z *= scale * wv.z; v[j].w *= scale * wv.w;
        }
    }
#pragma unroll
    for (int j = 0; j < 4; ++j) {
        us4 o = { f32_to_bf16_raw(v[j].x), f32_to_bf16_raw(v[j].y),
                  f32_to_bf16_raw(v[j].z), f32_to_bf16_raw(v[j].w) };
        dst[lane + 64 * j] = o;
    }
}

// ---------------------------------------------------------------- GEMM params
#define BM 128
#define BN 128
#define BK 64

// fused gemm1 (worklist): g = bf16(silu(A@W1^T) * (A@W3^T)) into gbuf
__global__ __launch_bounds__(256) void gemm1_kernel(
    const u16* __restrict__ Ag,
    const u16* __restrict__ w1f, const u16* __restrict__ w3f,
    const u16* __restrict__ w1s, const u16* __restrict__ w3s,
    u16* __restrict__ gbuf,
    const int* __restrict__ counts, const int* __restrict__ offs,
    const uint32_t* __restrict__ wl1) {
    const uint32_t w = wl1[blockIdx.y];
    if (w == 0xFFFFFFFFu) return;
    const int e    = w & 15;
    const int m0   = (w >> 4) & 0xFFFF;
    const int half = w >> 24;
    const int n0   = half * 2048 + blockIdx.x * BN;
    const int cnt  = counts[e];
    const int rowbase = offs[e];
    const u16* W1 = (e < NFRAC) ? w1f + (size_t)e * HFRAC * DIM
                                : w1s + (size_t)(e - NFRAC) * HSW * DIM;
    const u16* W3 = (e < NFRAC) ? w3f + (size_t)e * HFRAC * DIM
                                : w3s + (size_t)(e - NFRAC) * HSW * DIM;
    const u16* A = Ag + (size_t)(rowbase + m0) * DIM;

    __shared__ u16 sA[BM * BK];    // 16 KB each
    __shared__ u16 sB1[BN * BK];
    __shared__ u16 sB3[BN * BK];

    const int tid  = threadIdx.x;
    const int wave = tid >> 6;
    const int lane = tid & 63;
    const int wm = wave >> 1, wn = wave & 1;
    const int fr = lane & 15;
    const int quad = lane >> 4;

    floatx4 acc1[4][4], acc3[4][4];
    floatx4 zero = { 0.f, 0.f, 0.f, 0.f };
#pragma unroll
    for (int mt = 0; mt < 4; ++mt)
#pragma unroll
        for (int nt = 0; nt < 4; ++nt) { acc1[mt][nt] = zero; acc3[mt][nt] = zero; }

    const u16* gB1 = W1 + (size_t)n0 * DIM;
    const u16* gB3 = W3 + (size_t)n0 * DIM;

    for (int k0 = 0; k0 < DIM; k0 += BK) {
        stage_tile(A   + k0, DIM, sA,  wave, lane);
        stage_tile(gB1 + k0, DIM, sB1, wave, lane);
        stage_tile(gB3 + k0, DIM, sB3, wave, lane);
        __syncthreads();
#pragma unroll
        for (int ks = 0; ks < 2; ++ks) {
            const int q = ks * 4 + quad;
            bf16x8 af[4];
#pragma unroll
            for (int mt = 0; mt < 4; ++mt)
                af[mt] = frag_ld(sA, wm * 64 + mt * 16 + fr, q);
#pragma unroll
            for (int nt = 0; nt < 4; ++nt) {
                bf16x8 b1 = frag_ld(sB1, wn * 64 + nt * 16 + fr, q);
                bf16x8 b3 = frag_ld(sB3, wn * 64 + nt * 16 + fr, q);
#pragma unroll
                for (int mt = 0; mt < 4; ++mt) {
                    acc1[mt][nt] = __builtin_amdgcn_mfma_f32_16x16x32_bf16(
                        af[mt], b1, acc1[mt][nt], 0, 0, 0);
                    acc3[mt][nt] = __builtin_amdgcn_mfma_f32_16x16x32_bf16(
                        af[mt], b3, acc3[mt][nt], 0, 0, 0);
                }
            }
        }
        __syncthreads();
    }
#pragma unroll
    for (int mt = 0; mt < 4; ++mt)
#pragma unroll
        for (int nt = 0; nt < 4; ++nt)
#pragma unroll
            for (int r = 0; r < 4; ++r) {
                int row_local = m0 + wm * 64 + mt * 16 + quad * 4 + r;
                if (row_local >= cnt) continue;
                int col = n0 + wn * 64 + nt * 16 + fr;
                float h1 = acc1[mt][nt][r];
                float h3 = acc3[mt][nt][r];
                float g = (h1 / (1.0f + expf(-h1))) * h3;
                gbuf[(size_t)(rowbase + row_local) * HSW + col] = f32_to_bf16_raw(g);
            }
}

// fused gemm2 (worklist): y = g @ W2^T; atomicAdd combined result into out
__global__ __launch_bounds__(256) void gemm2_kernel(
    const u16* __restrict__ gbuf,
    const u16* __restrict__ w2f, const u16* __restrict__ w2s,
    const u16* __restrict__ Ag, const float* __restrict__ x,
    const float* __restrict__ frac_gamma,
    const int* __restrict__ rowtok, const float* __restrict__ co,
    const int* __restrict__ counts, const int* __restrict__ offs,
    const uint32_t* __restrict__ wl2,
    float* __restrict__ out) {
    const uint32_t w = wl2[blockIdx.y];
    if (w == 0xFFFFFFFFu) return;
    const int e  = w & 15;
    const int m0 = (w >> 4) & 0xFFFF;
    const int n0 = blockIdx.x * BN;
    const int cnt = counts[e];
    const int Ke = (e < NFRAC) ? HFRAC : HSW;
    const int rowbase = offs[e];
    const u16* W2 = (e < NFRAC) ? w2f + (size_t)e * DIM * HFRAC
                                : w2s + (size_t)(e - NFRAC) * DIM * HSW;
    const u16* A = gbuf + (size_t)(rowbase + m0) * HSW;

    __shared__ u16 sA[BM * BK];
    __shared__ u16 sB[BN * BK];

    const int tid  = threadIdx.x;
    const int wave = tid >> 6;
    const int lane = tid & 63;
    const int wm = wave >> 1, wn = wave & 1;
    const int fr = lane & 15;
    const int quad = lane >> 4;

    floatx4 acc[4][4];
    floatx4 zero = { 0.f, 0.f, 0.f, 0.f };
#pragma unroll
    for (int mt = 0; mt < 4; ++mt)
#pragma unroll
        for (int nt = 0; nt < 4; ++nt) acc[mt][nt] = zero;

    const u16* gB = W2 + (size_t)n0 * Ke;

    for (int k0 = 0; k0 < Ke; k0 += BK) {
        stage_tile(A  + k0, HSW, sA, wave, lane);
        stage_tile(gB + k0, Ke,  sB, wave, lane);
        __syncthreads();
#pragma unroll
        for (int ks = 0; ks < 2; ++ks) {
            const int q = ks * 4 + quad;
            bf16x8 af[4];
#pragma unroll
            for (int mt = 0; mt < 4; ++mt)
                af[mt] = frag_ld(sA, wm * 64 + mt * 16 + fr, q);
#pragma unroll
            for (int nt = 0; nt < 4; ++nt) {
                bf16x8 b = frag_ld(sB, wn * 64 + nt * 16 + fr, q);
#pragma unroll
                for (int mt = 0; mt < 4; ++mt)
                    acc[mt][nt] = __builtin_amdgcn_mfma_f32_16x16x32_bf16(
                        af[mt], b, acc[mt][nt], 0, 0, 0);
            }
        }
        __syncthreads();
    }
    const float* gamma = frac_gamma + (size_t)e * DIM;
#pragma unroll
    for (int mt = 0; mt < 4; ++mt)
#pragma unroll
        for (int nt = 0; nt < 4; ++nt)
#pragma unroll
            for (int rr = 0; rr < 4; ++rr) {
                int row_local = m0 + wm * 64 + mt * 16 + quad * 4 + rr;
                if (row_local >= cnt) continue;
                int r = rowbase + row_local;
                int col = n0 + wn * 64 + nt * 16 + fr;
                int info  = rowtok[r];
                int token = info & 0xFFFF;
                float coef = co[r];
                float y = acc[mt][nt][rr];
                float val;
                if (e < NFRAC) {
                    float xn = bf16_raw_to_f32(Ag[(size_t)r * DIM + col]);
                    val = coef * (gamma[col] * (xn + y) + x[(size_t)token * DIM + col]);
                } else {
                    val = coef * y;
                }
                atomicAdd(&out[(size_t)token * DIM + col], val);
            }
}

// ---------------------------------------------------------------- launch
extern "C" void kernel_launch(void* const* d_in, const int* in_sizes, int n_in,
                              void* d_out, int out_size, void* d_ws, size_t ws_size,
                              hipStream_t stream) {
    const float* x          = (const float*)d_in[0];
    const float* router_w   = (const float*)d_in[1];
    const float* frac_rms   = (const float*)d_in[2];
    const float* frac_w1    = (const float*)d_in[3];
    const float* frac_w2    = (const float*)d_in[4];
    const float* frac_w3    = (const float*)d_in[5];
    const float* frac_gamma = (const float*)d_in[6];
    const float* sw_w1      = (const float*)d_in[7];
    const float* sw_w2      = (const float*)d_in[8];
    const float* sw_w3      = (const float*)d_in[9];
    float* out = (float*)d_out;

    const size_t MB = 1u << 20;
    char* ws = (char*)d_ws;
    // meta
    int*      counts = (int*)ws;
    int*      cursor = (int*)(ws + 32);
    int*      offs   = (int*)(ws + 64);
    uint32_t* wl1    = (uint32_t*)(ws + 1024);    // 144*4 = 576 B
    uint32_t* wl2    = (uint32_t*)(ws + 2048);    // 72*4  = 288 B
    int*      re     = (int*)(ws + 4096);         // 32 KB -> 36864
    float*    rc     = (float*)(ws + 36864);      // 32 KB -> 69632
    int*      rowtok = (int*)(ws + 73728);        // ~33 KB
    float*    co     = (float*)(ws + 110592);     // ~33 KB
    // big buffers
    u16* Ag   = (u16*)(ws + 1 * MB);     // PAD_ROWS*1024*2 = 17.04 MB
    u16* gbuf = (u16*)(ws + 19 * MB);    // PAD_ROWS*4096*2 = 68.2 MB
    u16* w1f  = (u16*)(ws + 84 * MB);    // 16 MB
    u16* w3f  = (u16*)(ws + 100 * MB);   // 16 MB
    u16* w1s  = (u16*)(ws + 116 * MB);   // 32 MB
    u16* w3s  = (u16*)(ws + 148 * MB);   // 32 MB -> end 180 MB
    // w2 cache aliases w1/w3 cache (converted after gemm1 has consumed w1/w3)
    u16* w2f  = (u16*)(ws + 84 * MB);    // 16 MB
    u16* w2s  = (u16*)(ws + 100 * MB);   // 32 MB

    hipMemsetAsync(ws, 0, 256, stream);  // counts + cursor
    hipMemsetAsync(d_out, 0, (size_t)N_TOK * DIM * sizeof(float), stream);

    // weight cache: w1, w3 (w2 later, aliased). grid = elems/16384
    cvt_kernel<<<(NFRAC * HFRAC * DIM) / 16384, 256, 0, stream>>>(frac_w1, w1f);
    cvt_kernel<<<(NFRAC * HFRAC * DIM) / 16384, 256, 0, stream>>>(frac_w3, w3f);
    cvt_kernel<<<(NFRAC * HSW * DIM) / 16384, 256, 0, stream>>>(sw_w1, w1s);
    cvt_kernel<<<(NFRAC * HSW * DIM) / 16384, 256, 0, stream>>>(sw_w3, w3s);

    router_kernel<<<N_TOK / 4, 256, 0, stream>>>(x, router_w, re, rc, counts);
    offsets_kernel<<<1, 64, 0, stream>>>(counts, offs);
    build_wl_kernel<<<1, 64, 0, stream>>>(counts, wl1, wl2);
    scatter_kernel<<<N_TOK / 256, 256, 0, stream>>>(re, rc, offs, cursor, rowtok, co);
    gather_norm_kernel<<<PAD_ROWS / 4, 256, 0, stream>>>(x, frac_rms, rowtok, offs, Ag);

    gemm1_kernel<<<dim3(HSW / 2 / BN, WL1_MAX), 256, 0, stream>>>(
        Ag, w1f, w3f, w1s, w3s, gbuf, counts, offs, wl1);

    cvt_kernel<<<(NFRAC * DIM * HFRAC) / 16384, 256, 0, stream>>>(frac_w2, w2f);
    cvt_kernel<<<(NFRAC * DIM * HSW) / 16384, 256, 0, stream>>>(sw_w2, w2s);

    gemm2_kernel<<<dim3(DIM / BN, WL2_MAX), 256, 0, stream>>>(
        gbuf, w2f, w2s, Ag, x, frac_gamma, rowtok, co, counts, offs, wl2, out);
}